// Round 13
// baseline (541.523 us; speedup 1.0000x reference)
//
#include <hip/hip_runtime.h>
#include <hip/hip_fp16.h>
#include <cstdint>
#include <cstddef>

#define TPB 256
#define NWIN 8    // MUST equal XCD count for the FILL (window = blockIdx & 7
                  // keeps cnt/slot lines in ONE XCD's L2; r10: NWIN=16
                  // regressed mega 92->120 us). Reused for gather col-windows
                  // (3.2 MB xw1 window fits every XCD's 4 MB L2).
#define CAP 64    // slots per node (Poisson(16) tail: P(deg>64) ~ 3e-20)

using half8 = __attribute__((ext_vector_type(8))) _Float16;
using f32x4 = __attribute__((ext_vector_type(4))) float;

// ---------------------------------------------------------------------------
// SETUP (one dispatch, no cross-block deps):
//  blocks [0,16):   W1 fp32 -> fp16 MFMA B-frag order in global wf1 (32 KB)
//  blocks [16,24):  W2 -> wf2 (16 KB)
//  blocks [24, 24+nCnt): cnt[N] = 0
//  blocks [24+nCnt, ...): decode edge_index -> int2 pairs[E]; per-block
//       dtype self-detection from the first 256 int64 values.
// ---------------------------------------------------------------------------
__global__ void k_setup(const void* __restrict__ ei, int E, int N,
                        const float* __restrict__ W1, const float* __restrict__ W2,
                        _Float16* __restrict__ wf1, _Float16* __restrict__ wf2,
                        int* __restrict__ cnt, int2* __restrict__ pairs, int nCnt) {
    int b = blockIdx.x;
    if (b < 16) {
        int i = b * TPB + threadIdx.x;                   // 0..4095
        int k  = i >> 5;
        int n0 = (i & 31) * 4;
        float4 w = ((const float4*)W1)[i];
        int ct = n0 >> 4, kb = k >> 5;
        int lane0 = ((k >> 3) & 3) * 16 + (n0 & 15);
        int j = k & 7;
        int base = ((ct * 4 + kb) * 64 + lane0) * 8 + j;
        wf1[base]      = (_Float16)w.x;
        wf1[base + 8]  = (_Float16)w.y;
        wf1[base + 16] = (_Float16)w.z;
        wf1[base + 24] = (_Float16)w.w;
    } else if (b < 24) {
        int i = (b - 16) * TPB + threadIdx.x;            // 0..2047
        int k  = i >> 4;
        int n0 = (i & 15) * 4;
        float4 w = ((const float4*)W2)[i];
        int ct = n0 >> 4, kb = k >> 5;
        int lane0 = ((k >> 3) & 3) * 16 + (n0 & 15);
        int j = k & 7;
        int base = ((ct * 4 + kb) * 64 + lane0) * 8 + j;
        wf2[base]      = (_Float16)w.x;
        wf2[base + 8]  = (_Float16)w.y;
        wf2[base + 16] = (_Float16)w.z;
        wf2[base + 24] = (_Float16)w.w;
    } else if (b < 24 + nCnt) {
        int i = (b - 24) * TPB + threadIdx.x;
        if (i < N) cnt[i] = 0;
    } else {
        __shared__ int bad;
        if (threadIdx.x == 0) bad = 0;
        __syncthreads();
        if (threadIdx.x < 256) {
            long long v = ((const long long*)ei)[threadIdx.x];
            if (v < 0 || v >= (long long)N) bad = 1;
        }
        __syncthreads();
        int is64 = !bad;
        int base = ((b - 24 - nCnt) * TPB + threadIdx.x) * 4;
        if (base >= E) return;
        if (is64) {
            const long long* e64 = (const long long*)ei;
#pragma unroll
            for (int k = 0; k < 4; ++k)
                if (base + k < E)
                    pairs[base + k] = make_int2((int)e64[base + k],
                                                (int)e64[(long long)E + base + k]);
        } else {
            const int* e32 = (const int*)ei;
#pragma unroll
            for (int k = 0; k < 4; ++k)
                if (base + k < E)
                    pairs[base + k] = make_int2(e32[base + k], e32[E + base + k]);
        }
    }
}

// ---------------------------------------------------------------------------
// MEGA: block-split fused dispatch (unchanged from r12 — fill is at its
// device-scope atomic floor; ~45 G ops/s).
// ---------------------------------------------------------------------------
__global__ __launch_bounds__(256)
void k_mega(const int2* __restrict__ pairs, int E, int winRows, int N,
            int* __restrict__ cnt, int* __restrict__ slots,
            const float* __restrict__ x, const half8* __restrict__ wf1,
            __half* __restrict__ xw1, int nFill, int nGemm) {
    __shared__ __align__(16) _Float16 Of[4][16 * 136];   // 17 KB (gemm path)

    if ((int)blockIdx.x < nFill) {
        // ---------------- fill path ----------------
        const int w = blockIdx.x & (NWIN - 1);
        const int lo = w * winRows, hi = lo + winRows;
        const int nChunks = (E + 1023) >> 10;
        const int stride = nFill / NWIN;
        for (int chunk = blockIdx.x / NWIN; chunk < nChunks; chunk += stride) {
            int base = (chunk << 10) + threadIdx.x * 4;
            if (base >= E) continue;
            int2 p[4];
            if (base + 3 < E) {
                const int4* p4 = (const int4*)(pairs + base);
                int4 u0 = p4[0], u1 = p4[1];
                p[0] = make_int2(u0.x, u0.y); p[1] = make_int2(u0.z, u0.w);
                p[2] = make_int2(u1.x, u1.y); p[3] = make_int2(u1.z, u1.w);
            } else {
#pragma unroll
                for (int k = 0; k < 4; ++k)
                    p[k] = (base + k < E) ? pairs[base + k] : make_int2(-1, -1);
            }
            int pos[4];
#pragma unroll
            for (int k = 0; k < 4; ++k) {
                bool in = (p[k].x >= lo && p[k].x < hi);
                pos[k] = in ? atomicAdd(&cnt[p[k].x], 1) : -1;
            }
#pragma unroll
            for (int k = 0; k < 4; ++k)
                if (pos[k] >= 0 && pos[k] < CAP)
                    slots[(size_t)p[k].x * CAP + pos[k]] = p[k].y;
        }
    } else {
        // ---------------- gemm1 path (unscaled) ----------------
        const int gb = blockIdx.x - nFill;
        const int wave = threadIdx.x >> 6, lane = threadIdx.x & 63;
        const int m = lane & 15, quad = lane >> 4;
        const int nRowTiles = (N + 15) >> 4;

        for (int rt = gb * 4 + wave; rt < nRowTiles; rt += nGemm * 4) {
            const int row0 = rt * 16;
            const int arow = row0 + m;
            const bool rvalid = arow < N;
            const float* xrow = x + (size_t)(rvalid ? arow : 0) * 128;

            f32x4 acc[8];
#pragma unroll
            for (int ct = 0; ct < 8; ++ct) acc[ct] = (f32x4){0.f, 0.f, 0.f, 0.f};

#pragma unroll
            for (int kb = 0; kb < 4; ++kb) {
                const float4* ap = (const float4*)(xrow + kb * 32 + quad * 8);
                float4 a0 = ap[0], a1 = ap[1];
                half8 a;
                a[0] = (_Float16)a0.x; a[1] = (_Float16)a0.y;
                a[2] = (_Float16)a0.z; a[3] = (_Float16)a0.w;
                a[4] = (_Float16)a1.x; a[5] = (_Float16)a1.y;
                a[6] = (_Float16)a1.z; a[7] = (_Float16)a1.w;
#pragma unroll
                for (int ct = 0; ct < 8; ++ct) {
                    half8 b = wf1[(ct * 4 + kb) * 64 + lane];
                    acc[ct] = __builtin_amdgcn_mfma_f32_16x16x32_f16(a, b, acc[ct], 0, 0, 0);
                }
            }

            _Float16* myO = &Of[wave][0];
#pragma unroll
            for (int ct = 0; ct < 8; ++ct)
#pragma unroll
                for (int r = 0; r < 4; ++r)
                    myO[(quad * 4 + r) * 136 + ct * 16 + m] = (_Float16)acc[ct][r];
            int vr = N - row0; if (vr > 16) vr = 16;
            float4* dst = (float4*)(xw1 + (size_t)row0 * 128);
            for (int i = lane; i < vr * 16; i += 64) {
                int r = i >> 4, q = i & 15;
                dst[r * 16 + q] = *(const float4*)&myO[r * 136 + q * 8];
            }
        }
    }
}

// ---------------------------------------------------------------------------
// FUSED gather1 + gemm2. Block = 16 nodes.
// Phase 1 is COL-WINDOWED: outer loop over 8 source-node windows; only
// neighbors in the current 3.2 MB xw1 window are loaded -> window stays
// L2-resident in every XCD. Accumulators persist in registers. Branch is
// uniform within each 16-lane group (slot value is group-shared).
// ---------------------------------------------------------------------------
__global__ __launch_bounds__(256)
void k_g1g2(const __half* __restrict__ xw1, const int* __restrict__ cnt,
            const int* __restrict__ slots, const float* __restrict__ bias,
            const half8* __restrict__ wf2, __half* __restrict__ xw2, int N,
            int winRows) {
    __shared__ __align__(16) _Float16 Ht[16 * 136];   // h tile, padded
    __shared__ __align__(16) _Float16 Of[16 * 72];    // xw2 transpose

    const int row0 = blockIdx.x * 16;
    const int local = threadIdx.x >> 4;     // 0..15: node within tile
    const int lane16 = threadIdx.x & 15;    // feature quad: 8 halves
    const int node = row0 + local;

    // ---- phase 1: col-windowed gather ----
    {
        union { __half2 h2[4]; float4 f; } u;
        if (node < N) {
            int cn = cnt[node];
            int len = cn > CAP ? CAP : cn;
            float dvn = rsqrtf((float)cn + 1.0f);
            const int* sl = slots + (size_t)node * CAP;
            float acc[8];
            {
                float4 raw = *(const float4*)(xw1 + (size_t)node * 128 + lane16 * 8);
                const __half2* hp = (const __half2*)&raw;
#pragma unroll
                for (int k = 0; k < 4; ++k) {
                    float2 f = __half22float2(hp[k]);
                    acc[2 * k] = dvn * f.x; acc[2 * k + 1] = dvn * f.y;
                }
            }
            for (int win = 0; win < NWIN; ++win) {
                const int lo = win * winRows, hi = lo + winRows;
                int j = 0;
                for (; j + 3 < len; j += 4) {
                    int4 cc = *(const int4*)(sl + j);
#pragma unroll
                    for (int k = 0; k < 4; ++k) {
                        int c = (k == 0) ? cc.x : (k == 1) ? cc.y : (k == 2) ? cc.z : cc.w;
                        if (c >= lo && c < hi) {
                            float dv = rsqrtf((float)cnt[c] + 1.0f);
                            float4 raw = *(const float4*)(xw1 + (size_t)c * 128 + lane16 * 8);
                            const __half2* hp = (const __half2*)&raw;
#pragma unroll
                            for (int q = 0; q < 4; ++q) {
                                float2 f = __half22float2(hp[q]);
                                acc[2 * q]     = fmaf(dv, f.x, acc[2 * q]);
                                acc[2 * q + 1] = fmaf(dv, f.y, acc[2 * q + 1]);
                            }
                        }
                    }
                }
                for (; j < len; ++j) {
                    int c = sl[j];
                    if (c >= lo && c < hi) {
                        float dv = rsqrtf((float)cnt[c] + 1.0f);
                        float4 raw = *(const float4*)(xw1 + (size_t)c * 128 + lane16 * 8);
                        const __half2* hp = (const __half2*)&raw;
#pragma unroll
                        for (int q = 0; q < 4; ++q) {
                            float2 f = __half22float2(hp[q]);
                            acc[2 * q]     = fmaf(dv, f.x, acc[2 * q]);
                            acc[2 * q + 1] = fmaf(dv, f.y, acc[2 * q + 1]);
                        }
                    }
                }
            }
            float4 b01 = ((const float4*)bias)[lane16 * 2];
            float4 b23 = ((const float4*)bias)[lane16 * 2 + 1];
            float v[8];
            v[0] = b01.x + dvn * acc[0]; v[1] = b01.y + dvn * acc[1];
            v[2] = b01.z + dvn * acc[2]; v[3] = b01.w + dvn * acc[3];
            v[4] = b23.x + dvn * acc[4]; v[5] = b23.y + dvn * acc[5];
            v[6] = b23.z + dvn * acc[6]; v[7] = b23.w + dvn * acc[7];
#pragma unroll
            for (int k = 0; k < 4; ++k)
                u.h2[k] = __floats2half2_rn(fmaxf(v[2 * k], 0.f), fmaxf(v[2 * k + 1], 0.f));
        } else {
            u.f = make_float4(0.f, 0.f, 0.f, 0.f);
        }
        *(float4*)(Ht + local * 136 + lane16 * 8) = u.f;
    }
    __syncthreads();

    // ---- phase 2: MFMA h_tile @ W2, wave ct ----
    {
        const int wave = threadIdx.x >> 6, lane = threadIdx.x & 63;
        const int m = lane & 15, quad = lane >> 4;
        f32x4 acc = (f32x4){0.f, 0.f, 0.f, 0.f};
#pragma unroll
        for (int kb = 0; kb < 4; ++kb) {
            half8 a = *(const half8*)(Ht + m * 136 + kb * 32 + quad * 8);
            half8 b = wf2[(wave * 4 + kb) * 64 + lane];
            acc = __builtin_amdgcn_mfma_f32_16x16x32_f16(a, b, acc, 0, 0, 0);
        }
#pragma unroll
        for (int r = 0; r < 4; ++r)
            Of[(quad * 4 + r) * 72 + wave * 16 + m] = (_Float16)acc[r];
    }
    __syncthreads();
    {
        int vr = N - row0; if (vr > 16) vr = 16;
        float4* dst = (float4*)(xw2 + (size_t)row0 * 64);
        for (int i = threadIdx.x; i < vr * 8; i += TPB) {
            int r = i >> 3, q = i & 7;
            dst[r * 8 + q] = *(const float4*)&Of[r * 72 + q * 8];
        }
    }
}

// ---------------------------------------------------------------------------
// Capacity-CSR gather, layer 2 (F=64), COL-WINDOWED (1.6 MB xw2 window,
// L2-resident), FUSED bias + self-loop + norm + log_softmax.
// ---------------------------------------------------------------------------
__global__ void k_gather2_lsm(const __half* __restrict__ xws, const int* __restrict__ cnt,
                              const int* __restrict__ slots,
                              const float* __restrict__ bias, float* __restrict__ out,
                              int N, int winRows) {
    long long t = (long long)blockIdx.x * TPB + threadIdx.x;
    int node = (int)(t >> 4);
    int lane = (int)(t & 15);
    if (node >= N) return;
    int cn = cnt[node];
    int len = cn > CAP ? CAP : cn;
    float dvn = rsqrtf((float)cn + 1.0f);
    const int* sl = slots + (size_t)node * CAP;
    float a0, a1, a2, a3;
    {
        float2 raw = *(const float2*)(xws + (size_t)node * 64 + lane * 4);
        const __half2* hp = (const __half2*)&raw;
        float2 f0 = __half22float2(hp[0]), f1 = __half22float2(hp[1]);
        a0 = dvn * f0.x; a1 = dvn * f0.y; a2 = dvn * f1.x; a3 = dvn * f1.y;
    }
    for (int win = 0; win < NWIN; ++win) {
        const int lo = win * winRows, hi = lo + winRows;
        int j = 0;
        for (; j + 3 < len; j += 4) {
            int4 cc = *(const int4*)(sl + j);
#pragma unroll
            for (int k = 0; k < 4; ++k) {
                int c = (k == 0) ? cc.x : (k == 1) ? cc.y : (k == 2) ? cc.z : cc.w;
                if (c >= lo && c < hi) {
                    float dv = rsqrtf((float)cnt[c] + 1.0f);
                    float2 raw = *(const float2*)(xws + (size_t)c * 64 + lane * 4);
                    const __half2* hp = (const __half2*)&raw;
                    float2 f0 = __half22float2(hp[0]), f1 = __half22float2(hp[1]);
                    a0 = fmaf(dv, f0.x, a0); a1 = fmaf(dv, f0.y, a1);
                    a2 = fmaf(dv, f1.x, a2); a3 = fmaf(dv, f1.y, a3);
                }
            }
        }
        for (; j < len; ++j) {
            int c = sl[j];
            if (c >= lo && c < hi) {
                float dv = rsqrtf((float)cnt[c] + 1.0f);
                float2 raw = *(const float2*)(xws + (size_t)c * 64 + lane * 4);
                const __half2* hp = (const __half2*)&raw;
                float2 f0 = __half22float2(hp[0]), f1 = __half22float2(hp[1]);
                a0 = fmaf(dv, f0.x, a0); a1 = fmaf(dv, f0.y, a1);
                a2 = fmaf(dv, f1.x, a2); a3 = fmaf(dv, f1.y, a3);
            }
        }
    }
    float4 bb = ((const float4*)bias)[lane];
    float v0 = bb.x + dvn * a0, v1 = bb.y + dvn * a1;
    float v2 = bb.z + dvn * a2, v3 = bb.w + dvn * a3;

    float m = fmaxf(fmaxf(v0, v1), fmaxf(v2, v3));
#pragma unroll
    for (int off = 1; off < 16; off <<= 1) m = fmaxf(m, __shfl_xor(m, off));
    float s = expf(v0 - m) + expf(v1 - m) + expf(v2 - m) + expf(v3 - m);
#pragma unroll
    for (int off = 1; off < 16; off <<= 1) s += __shfl_xor(s, off);
    float ls = m + logf(s);
    ((float4*)(out + (size_t)node * 64))[lane] =
        make_float4(v0 - ls, v1 - ls, v2 - ls, v3 - ls);
}

// ---------------------------------------------------------------------------
extern "C" void kernel_launch(void* const* d_in, const int* in_sizes, int n_in,
                              void* d_out, int out_size, void* d_ws, size_t ws_size,
                              hipStream_t stream) {
    const float* x  = (const float*)d_in[0];
    const void*  ei = d_in[1];
    const float* W1 = (const float*)d_in[2];
    const float* b1 = (const float*)d_in[3];
    const float* W2 = (const float*)d_in[4];
    const float* b2 = (const float*)d_in[5];
    float* out = (float*)d_out;

    const int N = in_sizes[0] / 128;   // 100000
    const int E = in_sizes[1] / 2;     // 1600000

    char* base = (char*)d_ws;
    size_t off = 0;
    auto alloc = [&](size_t bytes) { char* p = base + off; off = (off + bytes + 255) & ~(size_t)255; return p; };
    int*      cnt   = (int*)alloc((size_t)N * sizeof(int));
    _Float16* wf1   = (_Float16*)alloc(128 * 128 * sizeof(_Float16));
    _Float16* wf2   = (_Float16*)alloc(128 * 64 * sizeof(_Float16));
    int2*     pairs = (int2*)alloc((size_t)E * sizeof(int2));
    int*      slots = (int*)alloc((size_t)N * CAP * sizeof(int));
    __half*   xw1   = (__half*)alloc((size_t)N * 128 * sizeof(__half));
    __half*   xw2   = (__half*)alloc((size_t)N * 64 * sizeof(__half));
    (void)ws_size;

    const int winRows = (N + NWIN - 1) / NWIN;
    const int nFill = 1024, nGemm = 512;
    const int nodeTiles = (N + 15) / 16;
    const int nCnt = (N + TPB - 1) / TPB;
    const int nDec = (E + TPB * 4 - 1) / (TPB * 4);

    k_setup<<<24 + nCnt + nDec, TPB, 0, stream>>>(ei, E, N, W1, W2, wf1, wf2,
                                                  cnt, pairs, nCnt);

    k_mega<<<nFill + nGemm, TPB, 0, stream>>>(pairs, E, winRows, N, cnt, slots,
                                              x, (const half8*)wf1, xw1, nFill, nGemm);

    k_g1g2<<<nodeTiles, TPB, 0, stream>>>(xw1, cnt, slots, b1, (const half8*)wf2,
                                          xw2, N, winRows);

    {
        long long t = (long long)N * 16;
        k_gather2_lsm<<<(int)((t + TPB - 1) / TPB), TPB, 0, stream>>>(xw2, cnt, slots,
                                                                      b2, out, N, winRows);
    }
}

// Round 14
// 287.029 us; speedup vs baseline: 1.8866x; 1.8866x over previous
//
#include <hip/hip_runtime.h>
#include <hip/hip_fp16.h>
#include <cstdint>
#include <cstddef>

#define TPB 256
#define NWIN 8    // MUST equal XCD count (fill scatter window = blockIdx & 7;
                  // r10: NWIN=16 spanned 2 XCDs -> mega 92->120 us).
                  // NOTE (r13): do NOT source-window the GATHERS — 8x slot
                  // re-walk + no phase coherence = 190 us vs 85. Gathers stay
                  // single-pass.
#define CAP 64    // slots per node (Poisson(16) tail: P(deg>64) ~ 3e-20)

using half8 = __attribute__((ext_vector_type(8))) _Float16;
using f32x4 = __attribute__((ext_vector_type(4))) float;

// ---------------------------------------------------------------------------
// SETUP (one dispatch, no cross-block deps):
//  blocks [0,16):   W1 fp32 -> fp16 MFMA B-frag order in global wf1 (32 KB)
//  blocks [16,24):  W2 -> wf2 (16 KB)
//  blocks [24, 24+nCnt): cnt[N] = 0
//  blocks [24+nCnt, ...): decode edge_index -> int2 pairs[E]; per-block
//       dtype self-detection from the first 256 int64 values.
// ---------------------------------------------------------------------------
__global__ void k_setup(const void* __restrict__ ei, int E, int N,
                        const float* __restrict__ W1, const float* __restrict__ W2,
                        _Float16* __restrict__ wf1, _Float16* __restrict__ wf2,
                        int* __restrict__ cnt, int2* __restrict__ pairs, int nCnt) {
    int b = blockIdx.x;
    if (b < 16) {
        int i = b * TPB + threadIdx.x;                   // 0..4095
        int k  = i >> 5;
        int n0 = (i & 31) * 4;
        float4 w = ((const float4*)W1)[i];
        int ct = n0 >> 4, kb = k >> 5;
        int lane0 = ((k >> 3) & 3) * 16 + (n0 & 15);
        int j = k & 7;
        int base = ((ct * 4 + kb) * 64 + lane0) * 8 + j;
        wf1[base]      = (_Float16)w.x;
        wf1[base + 8]  = (_Float16)w.y;
        wf1[base + 16] = (_Float16)w.z;
        wf1[base + 24] = (_Float16)w.w;
    } else if (b < 24) {
        int i = (b - 16) * TPB + threadIdx.x;            // 0..2047
        int k  = i >> 4;
        int n0 = (i & 15) * 4;
        float4 w = ((const float4*)W2)[i];
        int ct = n0 >> 4, kb = k >> 5;
        int lane0 = ((k >> 3) & 3) * 16 + (n0 & 15);
        int j = k & 7;
        int base = ((ct * 4 + kb) * 64 + lane0) * 8 + j;
        wf2[base]      = (_Float16)w.x;
        wf2[base + 8]  = (_Float16)w.y;
        wf2[base + 16] = (_Float16)w.z;
        wf2[base + 24] = (_Float16)w.w;
    } else if (b < 24 + nCnt) {
        int i = (b - 24) * TPB + threadIdx.x;
        if (i < N) cnt[i] = 0;
    } else {
        __shared__ int bad;
        if (threadIdx.x == 0) bad = 0;
        __syncthreads();
        if (threadIdx.x < 256) {
            long long v = ((const long long*)ei)[threadIdx.x];
            if (v < 0 || v >= (long long)N) bad = 1;
        }
        __syncthreads();
        int is64 = !bad;
        int base = ((b - 24 - nCnt) * TPB + threadIdx.x) * 4;
        if (base >= E) return;
        if (is64) {
            const long long* e64 = (const long long*)ei;
#pragma unroll
            for (int k = 0; k < 4; ++k)
                if (base + k < E)
                    pairs[base + k] = make_int2((int)e64[base + k],
                                                (int)e64[(long long)E + base + k]);
        } else {
            const int* e32 = (const int*)ei;
#pragma unroll
            for (int k = 0; k < 4; ++k)
                if (base + k < E)
                    pairs[base + k] = make_int2(e32[base + k], e32[E + base + k]);
        }
    }
}

// ---------------------------------------------------------------------------
// MEGA: block-split fused dispatch (fill at its device-scope atomic floor,
// ~45 G ops/s; gemm1 overlapped on the MFMA/HBM pipes).
// ---------------------------------------------------------------------------
__global__ __launch_bounds__(256)
void k_mega(const int2* __restrict__ pairs, int E, int winRows, int N,
            int* __restrict__ cnt, int* __restrict__ slots,
            const float* __restrict__ x, const half8* __restrict__ wf1,
            __half* __restrict__ xw1, int nFill, int nGemm) {
    __shared__ __align__(16) _Float16 Of[4][16 * 136];   // 17 KB (gemm path)

    if ((int)blockIdx.x < nFill) {
        // ---------------- fill path ----------------
        const int w = blockIdx.x & (NWIN - 1);
        const int lo = w * winRows, hi = lo + winRows;
        const int nChunks = (E + 1023) >> 10;
        const int stride = nFill / NWIN;
        for (int chunk = blockIdx.x / NWIN; chunk < nChunks; chunk += stride) {
            int base = (chunk << 10) + threadIdx.x * 4;
            if (base >= E) continue;
            int2 p[4];
            if (base + 3 < E) {
                const int4* p4 = (const int4*)(pairs + base);
                int4 u0 = p4[0], u1 = p4[1];
                p[0] = make_int2(u0.x, u0.y); p[1] = make_int2(u0.z, u0.w);
                p[2] = make_int2(u1.x, u1.y); p[3] = make_int2(u1.z, u1.w);
            } else {
#pragma unroll
                for (int k = 0; k < 4; ++k)
                    p[k] = (base + k < E) ? pairs[base + k] : make_int2(-1, -1);
            }
            int pos[4];
#pragma unroll
            for (int k = 0; k < 4; ++k) {
                bool in = (p[k].x >= lo && p[k].x < hi);
                pos[k] = in ? atomicAdd(&cnt[p[k].x], 1) : -1;
            }
#pragma unroll
            for (int k = 0; k < 4; ++k)
                if (pos[k] >= 0 && pos[k] < CAP)
                    slots[(size_t)p[k].x * CAP + pos[k]] = p[k].y;
        }
    } else {
        // ---------------- gemm1 path (unscaled) ----------------
        const int gb = blockIdx.x - nFill;
        const int wave = threadIdx.x >> 6, lane = threadIdx.x & 63;
        const int m = lane & 15, quad = lane >> 4;
        const int nRowTiles = (N + 15) >> 4;

        for (int rt = gb * 4 + wave; rt < nRowTiles; rt += nGemm * 4) {
            const int row0 = rt * 16;
            const int arow = row0 + m;
            const bool rvalid = arow < N;
            const float* xrow = x + (size_t)(rvalid ? arow : 0) * 128;

            f32x4 acc[8];
#pragma unroll
            for (int ct = 0; ct < 8; ++ct) acc[ct] = (f32x4){0.f, 0.f, 0.f, 0.f};

#pragma unroll
            for (int kb = 0; kb < 4; ++kb) {
                const float4* ap = (const float4*)(xrow + kb * 32 + quad * 8);
                float4 a0 = ap[0], a1 = ap[1];
                half8 a;
                a[0] = (_Float16)a0.x; a[1] = (_Float16)a0.y;
                a[2] = (_Float16)a0.z; a[3] = (_Float16)a0.w;
                a[4] = (_Float16)a1.x; a[5] = (_Float16)a1.y;
                a[6] = (_Float16)a1.z; a[7] = (_Float16)a1.w;
#pragma unroll
                for (int ct = 0; ct < 8; ++ct) {
                    half8 b = wf1[(ct * 4 + kb) * 64 + lane];
                    acc[ct] = __builtin_amdgcn_mfma_f32_16x16x32_f16(a, b, acc[ct], 0, 0, 0);
                }
            }

            _Float16* myO = &Of[wave][0];
#pragma unroll
            for (int ct = 0; ct < 8; ++ct)
#pragma unroll
                for (int r = 0; r < 4; ++r)
                    myO[(quad * 4 + r) * 136 + ct * 16 + m] = (_Float16)acc[ct][r];
            int vr = N - row0; if (vr > 16) vr = 16;
            float4* dst = (float4*)(xw1 + (size_t)row0 * 128);
            for (int i = lane; i < vr * 16; i += 64) {
                int r = i >> 4, q = i & 15;
                dst[r * 16 + q] = *(const float4*)&myO[r * 136 + q * 8];
            }
        }
    }
}

// ---------------------------------------------------------------------------
// FUSED gather1 + gemm2 (r12 structure: single pass, 4-edge unroll).
// ---------------------------------------------------------------------------
__global__ __launch_bounds__(256)
void k_g1g2(const __half* __restrict__ xw1, const int* __restrict__ cnt,
            const int* __restrict__ slots, const float* __restrict__ bias,
            const half8* __restrict__ wf2, __half* __restrict__ xw2, int N) {
    __shared__ __align__(16) _Float16 Ht[16 * 136];   // h tile, padded
    __shared__ __align__(16) _Float16 Of[16 * 72];    // xw2 transpose

    const int row0 = blockIdx.x * 16;
    const int local = threadIdx.x >> 4;     // 0..15: node within tile
    const int lane16 = threadIdx.x & 15;    // feature quad: 8 halves
    const int node = row0 + local;

    // ---- phase 1: gather ----
    {
        union { __half2 h2[4]; float4 f; } u;
        if (node < N) {
            int cn = cnt[node];
            int len = cn > CAP ? CAP : cn;
            float dvn = rsqrtf((float)cn + 1.0f);
            const int* sl = slots + (size_t)node * CAP;
            float acc[8];
            {
                float4 raw = *(const float4*)(xw1 + (size_t)node * 128 + lane16 * 8);
                const __half2* hp = (const __half2*)&raw;
#pragma unroll
                for (int k = 0; k < 4; ++k) {
                    float2 f = __half22float2(hp[k]);
                    acc[2 * k] = dvn * f.x; acc[2 * k + 1] = dvn * f.y;
                }
            }
            int j = 0;
            for (; j + 3 < len; j += 4) {
                int4 cc = *(const int4*)(sl + j);
                float dv0 = rsqrtf((float)cnt[cc.x] + 1.0f);
                float dv1 = rsqrtf((float)cnt[cc.y] + 1.0f);
                float dv2 = rsqrtf((float)cnt[cc.z] + 1.0f);
                float dv3 = rsqrtf((float)cnt[cc.w] + 1.0f);
                float4 raw0 = *(const float4*)(xw1 + (size_t)cc.x * 128 + lane16 * 8);
                float4 raw1 = *(const float4*)(xw1 + (size_t)cc.y * 128 + lane16 * 8);
                float4 raw2 = *(const float4*)(xw1 + (size_t)cc.z * 128 + lane16 * 8);
                float4 raw3 = *(const float4*)(xw1 + (size_t)cc.w * 128 + lane16 * 8);
                const __half2* h0 = (const __half2*)&raw0;
                const __half2* h1 = (const __half2*)&raw1;
                const __half2* h2 = (const __half2*)&raw2;
                const __half2* h3 = (const __half2*)&raw3;
#pragma unroll
                for (int k = 0; k < 4; ++k) {
                    float2 f0 = __half22float2(h0[k]);
                    float2 f1 = __half22float2(h1[k]);
                    float2 f2 = __half22float2(h2[k]);
                    float2 f3 = __half22float2(h3[k]);
                    acc[2 * k]     = fmaf(dv0, f0.x, fmaf(dv1, f1.x,
                                     fmaf(dv2, f2.x, fmaf(dv3, f3.x, acc[2 * k]))));
                    acc[2 * k + 1] = fmaf(dv0, f0.y, fmaf(dv1, f1.y,
                                     fmaf(dv2, f2.y, fmaf(dv3, f3.y, acc[2 * k + 1]))));
                }
            }
            for (; j < len; ++j) {
                int c = sl[j];
                float dv = rsqrtf((float)cnt[c] + 1.0f);
                float4 raw = *(const float4*)(xw1 + (size_t)c * 128 + lane16 * 8);
                const __half2* hp = (const __half2*)&raw;
#pragma unroll
                for (int k = 0; k < 4; ++k) {
                    float2 f = __half22float2(hp[k]);
                    acc[2 * k]     = fmaf(dv, f.x, acc[2 * k]);
                    acc[2 * k + 1] = fmaf(dv, f.y, acc[2 * k + 1]);
                }
            }
            float4 b01 = ((const float4*)bias)[lane16 * 2];
            float4 b23 = ((const float4*)bias)[lane16 * 2 + 1];
            float v[8];
            v[0] = b01.x + dvn * acc[0]; v[1] = b01.y + dvn * acc[1];
            v[2] = b01.z + dvn * acc[2]; v[3] = b01.w + dvn * acc[3];
            v[4] = b23.x + dvn * acc[4]; v[5] = b23.y + dvn * acc[5];
            v[6] = b23.z + dvn * acc[6]; v[7] = b23.w + dvn * acc[7];
#pragma unroll
            for (int k = 0; k < 4; ++k)
                u.h2[k] = __floats2half2_rn(fmaxf(v[2 * k], 0.f), fmaxf(v[2 * k + 1], 0.f));
        } else {
            u.f = make_float4(0.f, 0.f, 0.f, 0.f);
        }
        *(float4*)(Ht + local * 136 + lane16 * 8) = u.f;
    }
    __syncthreads();

    // ---- phase 2: MFMA h_tile @ W2, wave ct ----
    {
        const int wave = threadIdx.x >> 6, lane = threadIdx.x & 63;
        const int m = lane & 15, quad = lane >> 4;
        f32x4 acc = (f32x4){0.f, 0.f, 0.f, 0.f};
#pragma unroll
        for (int kb = 0; kb < 4; ++kb) {
            half8 a = *(const half8*)(Ht + m * 136 + kb * 32 + quad * 8);
            half8 b = wf2[(wave * 4 + kb) * 64 + lane];
            acc = __builtin_amdgcn_mfma_f32_16x16x32_f16(a, b, acc, 0, 0, 0);
        }
#pragma unroll
        for (int r = 0; r < 4; ++r)
            Of[(quad * 4 + r) * 72 + wave * 16 + m] = (_Float16)acc[r];
    }
    __syncthreads();
    {
        int vr = N - row0; if (vr > 16) vr = 16;
        float4* dst = (float4*)(xw2 + (size_t)row0 * 64);
        for (int i = threadIdx.x; i < vr * 8; i += TPB) {
            int r = i >> 3, q = i & 7;
            dst[r * 8 + q] = *(const float4*)&Of[r * 72 + q * 8];
        }
    }
}

// ---------------------------------------------------------------------------
// Capacity-CSR gather, layer 2 (F=64, fp16 UNSCALED src), FUSED bias +
// self-loop + norm (rsqrt inline) + log_softmax. Single pass, 4-edge unroll.
// ---------------------------------------------------------------------------
__global__ void k_gather2_lsm(const __half* __restrict__ xws, const int* __restrict__ cnt,
                              const int* __restrict__ slots,
                              const float* __restrict__ bias, float* __restrict__ out, int N) {
    long long t = (long long)blockIdx.x * TPB + threadIdx.x;
    int node = (int)(t >> 4);
    int lane = (int)(t & 15);
    if (node >= N) return;
    int cn = cnt[node];
    int len = cn > CAP ? CAP : cn;
    float dvn = rsqrtf((float)cn + 1.0f);
    const int* sl = slots + (size_t)node * CAP;
    float a0, a1, a2, a3;
    {
        float2 raw = *(const float2*)(xws + (size_t)node * 64 + lane * 4);
        const __half2* hp = (const __half2*)&raw;
        float2 f0 = __half22float2(hp[0]), f1 = __half22float2(hp[1]);
        a0 = dvn * f0.x; a1 = dvn * f0.y; a2 = dvn * f1.x; a3 = dvn * f1.y;
    }
    int j = 0;
    for (; j + 3 < len; j += 4) {
        int4 cc = *(const int4*)(sl + j);
        float dv0 = rsqrtf((float)cnt[cc.x] + 1.0f);
        float dv1 = rsqrtf((float)cnt[cc.y] + 1.0f);
        float dv2 = rsqrtf((float)cnt[cc.z] + 1.0f);
        float dv3 = rsqrtf((float)cnt[cc.w] + 1.0f);
        float2 raw0 = *(const float2*)(xws + (size_t)cc.x * 64 + lane * 4);
        float2 raw1 = *(const float2*)(xws + (size_t)cc.y * 64 + lane * 4);
        float2 raw2 = *(const float2*)(xws + (size_t)cc.z * 64 + lane * 4);
        float2 raw3 = *(const float2*)(xws + (size_t)cc.w * 64 + lane * 4);
        const __half2* h0 = (const __half2*)&raw0;
        const __half2* h1 = (const __half2*)&raw1;
        const __half2* h2 = (const __half2*)&raw2;
        const __half2* h3 = (const __half2*)&raw3;
        float2 f00 = __half22float2(h0[0]), f01 = __half22float2(h0[1]);
        float2 f10 = __half22float2(h1[0]), f11 = __half22float2(h1[1]);
        float2 f20 = __half22float2(h2[0]), f21 = __half22float2(h2[1]);
        float2 f30 = __half22float2(h3[0]), f31 = __half22float2(h3[1]);
        a0 = fmaf(dv0, f00.x, fmaf(dv1, f10.x, fmaf(dv2, f20.x, fmaf(dv3, f30.x, a0))));
        a1 = fmaf(dv0, f00.y, fmaf(dv1, f10.y, fmaf(dv2, f20.y, fmaf(dv3, f30.y, a1))));
        a2 = fmaf(dv0, f01.x, fmaf(dv1, f11.x, fmaf(dv2, f21.x, fmaf(dv3, f31.x, a2))));
        a3 = fmaf(dv0, f01.y, fmaf(dv1, f11.y, fmaf(dv2, f21.y, fmaf(dv3, f31.y, a3))));
    }
    for (; j < len; ++j) {
        int c = sl[j];
        float dv = rsqrtf((float)cnt[c] + 1.0f);
        float2 raw = *(const float2*)(xws + (size_t)c * 64 + lane * 4);
        const __half2* hp = (const __half2*)&raw;
        float2 f0 = __half22float2(hp[0]), f1 = __half22float2(hp[1]);
        a0 = fmaf(dv, f0.x, a0); a1 = fmaf(dv, f0.y, a1);
        a2 = fmaf(dv, f1.x, a2); a3 = fmaf(dv, f1.y, a3);
    }
    float4 bb = ((const float4*)bias)[lane];
    float v0 = bb.x + dvn * a0, v1 = bb.y + dvn * a1;
    float v2 = bb.z + dvn * a2, v3 = bb.w + dvn * a3;

    float m = fmaxf(fmaxf(v0, v1), fmaxf(v2, v3));
#pragma unroll
    for (int off = 1; off < 16; off <<= 1) m = fmaxf(m, __shfl_xor(m, off));
    float s = expf(v0 - m) + expf(v1 - m) + expf(v2 - m) + expf(v3 - m);
#pragma unroll
    for (int off = 1; off < 16; off <<= 1) s += __shfl_xor(s, off);
    float ls = m + logf(s);
    ((float4*)(out + (size_t)node * 64))[lane] =
        make_float4(v0 - ls, v1 - ls, v2 - ls, v3 - ls);
}

// ---------------------------------------------------------------------------
extern "C" void kernel_launch(void* const* d_in, const int* in_sizes, int n_in,
                              void* d_out, int out_size, void* d_ws, size_t ws_size,
                              hipStream_t stream) {
    const float* x  = (const float*)d_in[0];
    const void*  ei = d_in[1];
    const float* W1 = (const float*)d_in[2];
    const float* b1 = (const float*)d_in[3];
    const float* W2 = (const float*)d_in[4];
    const float* b2 = (const float*)d_in[5];
    float* out = (float*)d_out;

    const int N = in_sizes[0] / 128;   // 100000
    const int E = in_sizes[1] / 2;     // 1600000

    char* base = (char*)d_ws;
    size_t off = 0;
    auto alloc = [&](size_t bytes) { char* p = base + off; off = (off + bytes + 255) & ~(size_t)255; return p; };
    int*      cnt   = (int*)alloc((size_t)N * sizeof(int));
    _Float16* wf1   = (_Float16*)alloc(128 * 128 * sizeof(_Float16));
    _Float16* wf2   = (_Float16*)alloc(128 * 64 * sizeof(_Float16));
    int2*     pairs = (int2*)alloc((size_t)E * sizeof(int2));
    int*      slots = (int*)alloc((size_t)N * CAP * sizeof(int));
    __half*   xw1   = (__half*)alloc((size_t)N * 128 * sizeof(__half));
    __half*   xw2   = (__half*)alloc((size_t)N * 64 * sizeof(__half));
    (void)ws_size;

    const int winRows = (N + NWIN - 1) / NWIN;
    const int nFill = 1024, nGemm = 512;
    const int nodeTiles = (N + 15) / 16;
    const int nCnt = (N + TPB - 1) / TPB;
    const int nDec = (E + TPB * 4 - 1) / (TPB * 4);

    k_setup<<<24 + nCnt + nDec, TPB, 0, stream>>>(ei, E, N, W1, W2, wf1, wf2,
                                                  cnt, pairs, nCnt);

    k_mega<<<nFill + nGemm, TPB, 0, stream>>>(pairs, E, winRows, N, cnt, slots,
                                              x, (const half8*)wf1, xw1, nFill, nGemm);

    k_g1g2<<<nodeTiles, TPB, 0, stream>>>(xw1, cnt, slots, b1, (const half8*)wf2, xw2, N);

    {
        long long t = (long long)N * 16;
        k_gather2_lsm<<<(int)((t + TPB - 1) / TPB), TPB, 0, stream>>>(xw2, cnt, slots, b2, out, N);
    }
}